// Round 1
// baseline (3000.864 us; speedup 1.0000x reference)
//
#include <hip/hip_runtime.h>
#include <math.h>

#define D 128
#define TE 16
#define TN 16

__device__ __forceinline__ float silu_f(float x) {
    return x / (1.0f + __expf(-x));
}

// out[0 : N*D]        <- 0   (agg accumulator, later overwritten with h_out)
// out[N*D : N*D+N*3]  <- pos (pos_out base for scatter-add)
__global__ __launch_bounds__(256) void egnn_init(
    const float* __restrict__ pos, float* __restrict__ out, int N)
{
    int stride = gridDim.x * blockDim.x;
    int hd = N * D;
    int total = hd + N * 3;
    for (int i = blockIdx.x * blockDim.x + threadIdx.x; i < total; i += stride) {
        out[i] = (i < hd) ? 0.0f : pos[i - hd];
    }
}

__global__ __launch_bounds__(256) void egnn_edge(
    const float* __restrict__ h, const float* __restrict__ pos,
    const int* __restrict__ eidx,
    const float* __restrict__ We1, const float* __restrict__ be1,
    const float* __restrict__ We2, const float* __restrict__ be2,
    const float* __restrict__ Wc1, const float* __restrict__ bc1,
    const float* __restrict__ Wc2,
    float* __restrict__ agg, float* __restrict__ pos_out, int E)
{
    __shared__ __align__(16) float ein[TE][260];   // [0:128)=h[row], [128:256)=h[col], [256]=dist
    __shared__ __align__(16) float t1[TE][D];      // layer1 out, later coord-layer1 out
    __shared__ __align__(16) float msg[TE][D];
    __shared__ int   erow[TE];
    __shared__ int   ecol[TE];
    __shared__ float ediff[TE][3];
    __shared__ float edist[TE];

    const int tid = threadIdx.x;
    const int e0 = blockIdx.x * TE;

    // per-edge scalar setup
    if (tid < TE) {
        int e = e0 + tid;
        int r = 0, c = 0;
        if (e < E) { r = eidx[e]; c = eidx[E + e]; }
        erow[tid] = r; ecol[tid] = c;
        float dx = pos[r*3+0] - pos[c*3+0];
        float dy = pos[r*3+1] - pos[c*3+1];
        float dz = pos[r*3+2] - pos[c*3+2];
        float dd = sqrtf(dx*dx + dy*dy + dz*dz);
        dd = fmaxf(dd, 1e-6f);
        ediff[tid][0] = dx; ediff[tid][1] = dy; ediff[tid][2] = dz;
        edist[tid] = dd;
        ein[tid][256] = dd;
    }
    __syncthreads();

    // gather h[row] | h[col] into LDS (coalesced 512B segments)
    {
        int jj = tid & (D - 1);
        #pragma unroll
        for (int e = 0; e < TE; ++e) {
            int node = (tid < D) ? erow[e] : ecol[e];
            ein[e][tid] = h[(size_t)node * D + jj];
        }
    }
    __syncthreads();

    const int j0 = tid & 63;   // features j0 and j0+64
    const int eg = tid >> 6;   // wave id 0..3; edges eg+4i (wave-uniform -> LDS broadcast)

    // ---- edge layer 1: t1 = silu(ein @ We1 + be1), K = 257 ----
    {
        float acc[4][2];
        #pragma unroll
        for (int i = 0; i < 4; ++i) { acc[i][0] = 0.f; acc[i][1] = 0.f; }
        for (int k = 0; k < 256; k += 4) {
            float4 a[4];
            #pragma unroll
            for (int i = 0; i < 4; ++i)
                a[i] = *(const float4*)&ein[eg + 4*i][k];
            #pragma unroll
            for (int q = 0; q < 4; ++q) {
                float w0 = We1[(k + q) * D + j0];
                float w1 = We1[(k + q) * D + j0 + 64];
                #pragma unroll
                for (int i = 0; i < 4; ++i) {
                    float av = (&a[i].x)[q];
                    acc[i][0] = fmaf(av, w0, acc[i][0]);
                    acc[i][1] = fmaf(av, w1, acc[i][1]);
                }
            }
        }
        float wd0 = We1[256 * D + j0];
        float wd1 = We1[256 * D + j0 + 64];
        float b0 = be1[j0], b1 = be1[j0 + 64];
        #pragma unroll
        for (int i = 0; i < 4; ++i) {
            int e = eg + 4*i;
            float dd = ein[e][256];
            t1[e][j0]      = silu_f(fmaf(dd, wd0, acc[i][0]) + b0);
            t1[e][j0 + 64] = silu_f(fmaf(dd, wd1, acc[i][1]) + b1);
        }
    }
    __syncthreads();

    // ---- edge layer 2: msg = silu(t1 @ We2 + be2), K = 128 ----
    {
        float acc[4][2];
        #pragma unroll
        for (int i = 0; i < 4; ++i) { acc[i][0] = 0.f; acc[i][1] = 0.f; }
        for (int k = 0; k < D; k += 4) {
            float4 a[4];
            #pragma unroll
            for (int i = 0; i < 4; ++i)
                a[i] = *(const float4*)&t1[eg + 4*i][k];
            #pragma unroll
            for (int q = 0; q < 4; ++q) {
                float w0 = We2[(k + q) * D + j0];
                float w1 = We2[(k + q) * D + j0 + 64];
                #pragma unroll
                for (int i = 0; i < 4; ++i) {
                    float av = (&a[i].x)[q];
                    acc[i][0] = fmaf(av, w0, acc[i][0]);
                    acc[i][1] = fmaf(av, w1, acc[i][1]);
                }
            }
        }
        float b0 = be2[j0], b1 = be2[j0 + 64];
        #pragma unroll
        for (int i = 0; i < 4; ++i) {
            int e = eg + 4*i;
            msg[e][j0]      = silu_f(acc[i][0] + b0);
            msg[e][j0 + 64] = silu_f(acc[i][1] + b1);
        }
    }
    __syncthreads();

    // ---- coord layer 1: t1 = silu(msg @ Wc1 + bc1), K = 128 (t1 reused) ----
    {
        float acc[4][2];
        #pragma unroll
        for (int i = 0; i < 4; ++i) { acc[i][0] = 0.f; acc[i][1] = 0.f; }
        for (int k = 0; k < D; k += 4) {
            float4 a[4];
            #pragma unroll
            for (int i = 0; i < 4; ++i)
                a[i] = *(const float4*)&msg[eg + 4*i][k];
            #pragma unroll
            for (int q = 0; q < 4; ++q) {
                float w0 = Wc1[(k + q) * D + j0];
                float w1 = Wc1[(k + q) * D + j0 + 64];
                #pragma unroll
                for (int i = 0; i < 4; ++i) {
                    float av = (&a[i].x)[q];
                    acc[i][0] = fmaf(av, w0, acc[i][0]);
                    acc[i][1] = fmaf(av, w1, acc[i][1]);
                }
            }
        }
        float b0 = bc1[j0], b1 = bc1[j0 + 64];
        #pragma unroll
        for (int i = 0; i < 4; ++i) {
            int e = eg + 4*i;
            t1[e][j0]      = silu_f(acc[i][0] + b0);
            t1[e][j0 + 64] = silu_f(acc[i][1] + b1);
        }
    }
    __syncthreads();

    // ---- coord layer 2 + pos scatter: w = clip(t1 @ Wc2, -1, 1) ----
    {
        int e = tid >> 4;      // 16 threads per edge
        int l = tid & 15;
        float p = 0.f;
        for (int k = l; k < D; k += 16)
            p += t1[e][k] * Wc2[k];
        p += __shfl_down(p, 8, 16);
        p += __shfl_down(p, 4, 16);
        p += __shfl_down(p, 2, 16);
        p += __shfl_down(p, 1, 16);
        if (l == 0 && (e0 + e) < E) {
            float cw = fminf(1.0f, fmaxf(-1.0f, p));
            float s = cw / edist[e];
            int r = erow[e];
            atomicAdd(&pos_out[r*3+0], ediff[e][0] * s);
            atomicAdd(&pos_out[r*3+1], ediff[e][1] * s);
            atomicAdd(&pos_out[r*3+2], ediff[e][2] * s);
        }
    }

    // ---- msg scatter into agg ----
    {
        #pragma unroll
        for (int i = 0; i < 4; ++i) {
            int e = eg + 4*i;
            if ((e0 + e) < E) {
                int r = erow[e];
                atomicAdd(&agg[(size_t)r * D + j0],      msg[e][j0]);
                atomicAdd(&agg[(size_t)r * D + j0 + 64], msg[e][j0 + 64]);
            }
        }
    }
}

// out rows hold agg on entry; overwritten with h_out (block-disjoint rows -> safe)
__global__ __launch_bounds__(256) void egnn_node(
    const float* __restrict__ h,
    const float* __restrict__ Wn1, const float* __restrict__ bn1,
    const float* __restrict__ Wn2, const float* __restrict__ bn2,
    float* __restrict__ out, int N)
{
    __shared__ __align__(16) float hin[TN][256];   // [0:128)=h, [128:256)=agg
    __shared__ __align__(16) float t1[TN][D];

    const int tid = threadIdx.x;
    const int n0 = blockIdx.x * TN;

    {
        int jj = tid & (D - 1);
        #pragma unroll
        for (int n = 0; n < TN; ++n) {
            int node = n0 + n;
            if (node >= N) node = N - 1;
            hin[n][tid] = (tid < D) ? h[(size_t)node * D + jj]
                                    : out[(size_t)node * D + jj];
        }
    }
    __syncthreads();

    const int j0 = tid & 63;
    const int ng = tid >> 6;

    // ---- node layer 1: t1 = silu(hin @ Wn1 + bn1), K = 256 ----
    {
        float acc[4][2];
        #pragma unroll
        for (int i = 0; i < 4; ++i) { acc[i][0] = 0.f; acc[i][1] = 0.f; }
        for (int k = 0; k < 256; k += 4) {
            float4 a[4];
            #pragma unroll
            for (int i = 0; i < 4; ++i)
                a[i] = *(const float4*)&hin[ng + 4*i][k];
            #pragma unroll
            for (int q = 0; q < 4; ++q) {
                float w0 = Wn1[(k + q) * D + j0];
                float w1 = Wn1[(k + q) * D + j0 + 64];
                #pragma unroll
                for (int i = 0; i < 4; ++i) {
                    float av = (&a[i].x)[q];
                    acc[i][0] = fmaf(av, w0, acc[i][0]);
                    acc[i][1] = fmaf(av, w1, acc[i][1]);
                }
            }
        }
        float b0 = bn1[j0], b1 = bn1[j0 + 64];
        #pragma unroll
        for (int i = 0; i < 4; ++i) {
            int n = ng + 4*i;
            t1[n][j0]      = silu_f(acc[i][0] + b0);
            t1[n][j0 + 64] = silu_f(acc[i][1] + b1);
        }
    }
    __syncthreads();

    // ---- node layer 2 + residual: out = h + t1 @ Wn2 + bn2, K = 128 ----
    {
        float acc[4][2];
        #pragma unroll
        for (int i = 0; i < 4; ++i) { acc[i][0] = 0.f; acc[i][1] = 0.f; }
        for (int k = 0; k < D; k += 4) {
            float4 a[4];
            #pragma unroll
            for (int i = 0; i < 4; ++i)
                a[i] = *(const float4*)&t1[ng + 4*i][k];
            #pragma unroll
            for (int q = 0; q < 4; ++q) {
                float w0 = Wn2[(k + q) * D + j0];
                float w1 = Wn2[(k + q) * D + j0 + 64];
                #pragma unroll
                for (int i = 0; i < 4; ++i) {
                    float av = (&a[i].x)[q];
                    acc[i][0] = fmaf(av, w0, acc[i][0]);
                    acc[i][1] = fmaf(av, w1, acc[i][1]);
                }
            }
        }
        float b0 = bn2[j0], b1 = bn2[j0 + 64];
        #pragma unroll
        for (int i = 0; i < 4; ++i) {
            int node = n0 + ng + 4*i;
            if (node < N) {
                out[(size_t)node * D + j0]      = h[(size_t)node * D + j0]      + acc[i][0] + b0;
                out[(size_t)node * D + j0 + 64] = h[(size_t)node * D + j0 + 64] + acc[i][1] + b1;
            }
        }
    }
}

extern "C" void kernel_launch(void* const* d_in, const int* in_sizes, int n_in,
                              void* d_out, int out_size, void* d_ws, size_t ws_size,
                              hipStream_t stream)
{
    const float* h   = (const float*)d_in[0];
    const float* pos = (const float*)d_in[1];
    const int*   eidx= (const int*)d_in[2];
    const float* We1 = (const float*)d_in[3];
    const float* be1 = (const float*)d_in[4];
    const float* We2 = (const float*)d_in[5];
    const float* be2 = (const float*)d_in[6];
    const float* Wn1 = (const float*)d_in[7];
    const float* bn1 = (const float*)d_in[8];
    const float* Wn2 = (const float*)d_in[9];
    const float* bn2 = (const float*)d_in[10];
    const float* Wc1 = (const float*)d_in[11];
    const float* bc1 = (const float*)d_in[12];
    const float* Wc2 = (const float*)d_in[13];

    const int N = in_sizes[0] / D;
    const int E = in_sizes[2] / 2;

    float* out     = (float*)d_out;
    float* agg     = out;                      // h-region doubles as agg accumulator
    float* pos_out = out + (size_t)N * D;

    egnn_init<<<2048, 256, 0, stream>>>(pos, out, N);
    egnn_edge<<<(E + TE - 1) / TE, 256, 0, stream>>>(
        h, pos, eidx, We1, be1, We2, be2, Wc1, bc1, Wc2, agg, pos_out, E);
    egnn_node<<<(N + TN - 1) / TN, 256, 0, stream>>>(
        h, Wn1, bn1, Wn2, bn2, out, N);
}

// Round 2
// 995.263 us; speedup vs baseline: 3.0151x; 3.0151x over previous
//
#include <hip/hip_runtime.h>
#include <math.h>

#define D 128

typedef unsigned short u16;
typedef __attribute__((ext_vector_type(8))) short bf16x8;
typedef __attribute__((ext_vector_type(4))) float f32x4;
typedef __attribute__((ext_vector_type(4))) unsigned short u16x4;

__device__ __forceinline__ float silu_f(float x) {
    return x / (1.0f + __expf(-x));
}
__device__ __forceinline__ u16 f2bf(float x) {
    union { float f; unsigned int u; } v; v.f = x;
    unsigned int r = v.u + 0x7fffu + ((v.u >> 16) & 1u);
    return (u16)(r >> 16);
}
__device__ __forceinline__ float bf2f(u16 u) {
    union { unsigned int u; float f; } v; v.u = ((unsigned int)u) << 16; return v.f;
}

// ---------------- init: zero agg region, copy pos -> pos_out ----------------
__global__ __launch_bounds__(256) void egnn_init(
    const float* __restrict__ pos, float* __restrict__ out, int N)
{
    int stride = gridDim.x * blockDim.x;
    int hd = N * D;
    int total = hd + N * 3;
    for (int i = blockIdx.x * blockDim.x + threadIdx.x; i < total; i += stride)
        out[i] = (i < hd) ? 0.0f : pos[i - hd];
}

// ---------------- prep: weights -> fragment-ordered bf16 in ws ----------------
// frag order for 16x16x32 MFMA B-operand: elem(nt,kk,lane,j) = W[k*128+n],
//   k = kk*32 + (lane>>4)*8 + j,  n = nt*16 + (lane&15)
// ws layout (ushort): We1F[32768] We2F[16384] Wc1F[16384] Wn1F[32768] Wn2F[16384], then We1r fp32[128]
__global__ __launch_bounds__(256) void egnn_prep(
    const float* __restrict__ We1, const float* __restrict__ We2,
    const float* __restrict__ Wc1, const float* __restrict__ Wn1,
    const float* __restrict__ Wn2, u16* __restrict__ ws)
{
    int i = blockIdx.x * blockDim.x + threadIdx.x;   // grid = 32768 threads
    u16* We1F = ws;
    u16* We2F = ws + 32768;
    u16* Wc1F = ws + 49152;
    u16* Wn1F = ws + 65536;
    u16* Wn2F = ws + 98304;
    float* We1r = (float*)(ws + 114688);

    if (i < 32768) {   // K=256 matrices
        int j = i & 7, l = (i >> 3) & 63, kk = (i >> 9) & 7, nt = i >> 12;
        int k = kk * 32 + (l >> 4) * 8 + j;
        int n = nt * 16 + (l & 15);
        We1F[i] = f2bf(We1[k * D + n]);
        Wn1F[i] = f2bf(Wn1[k * D + n]);
    }
    if (i < 16384) {   // K=128 matrices
        int j = i & 7, l = (i >> 3) & 63, kk = (i >> 9) & 3, nt = i >> 11;
        int k = kk * 32 + (l >> 4) * 8 + j;
        int n = nt * 16 + (l & 15);
        We2F[i] = f2bf(We2[k * D + n]);
        Wc1F[i] = f2bf(Wc1[k * D + n]);
        Wn2F[i] = f2bf(Wn2[k * D + n]);
    }
    if (i < 128) We1r[i] = We1[256 * D + i];   // dist column of We1
}

// ---------------- edge kernel: MFMA ----------------
// 64 edges/block, 4 waves, each wave owns a 16-edge m-tile (rows w*16..w*16+15).
// After the gather sync, each wave only touches its own LDS rows -> no
// inter-layer __syncthreads needed.
__global__ __launch_bounds__(256, 3) void egnn_edge_mfma(
    const float* __restrict__ h, const float* __restrict__ pos,
    const int* __restrict__ eidx,
    const u16* __restrict__ We1F, const float* __restrict__ We1r,
    const float* __restrict__ be1,
    const u16* __restrict__ We2F, const float* __restrict__ be2,
    const u16* __restrict__ Wc1F, const float* __restrict__ bc1,
    const float* __restrict__ Wc2,
    float* __restrict__ agg, float* __restrict__ pos_out, int E)
{
    __shared__ u16 A[64][264];   // gathered [h_row | h_col] bf16; later msg (cols 0..127)
    __shared__ u16 T[64][136];   // ping: t1 (layer1 out), later t2 (coord1 out)
    __shared__ int erow[64], ecol[64];
    __shared__ float ediff[64][3], edist[64];

    const int tid = threadIdx.x;
    const int w = tid >> 6, l = tid & 63;
    const int q = l >> 4, m = l & 15;
    const int e0 = blockIdx.x * 64;

    if (tid < 64) {
        int e = e0 + tid;
        int r = 0, c = 0;
        if (e < E) { r = eidx[e]; c = eidx[E + e]; }
        erow[tid] = r; ecol[tid] = c;
        float dx = pos[r*3+0] - pos[c*3+0];
        float dy = pos[r*3+1] - pos[c*3+1];
        float dz = pos[r*3+2] - pos[c*3+2];
        float dd = fmaxf(sqrtf(dx*dx + dy*dy + dz*dz), 1e-6f);
        ediff[tid][0] = dx; ediff[tid][1] = dy; ediff[tid][2] = dz;
        edist[tid] = dd;
    }
    __syncthreads();

    // gather h[row] | h[col] -> bf16 LDS. wave w loads edge p*4+w each pass;
    // lanes 0..31 = row-node halves, 32..63 = col-node halves. 512B coalesced.
    #pragma unroll
    for (int p = 0; p < 16; ++p) {
        int el = p * 4 + w;
        int node = (l < 32) ? erow[el] : ecol[el];
        int f0 = (l & 31) * 4;
        float4 v = *(const float4*)(h + (size_t)node * D + f0);
        u16x4 b; b.x = f2bf(v.x); b.y = f2bf(v.y); b.z = f2bf(v.z); b.w = f2bf(v.w);
        *(u16x4*)&A[el][(l >> 5) * 128 + f0] = b;
    }
    __syncthreads();

    // ---- layer 1: t1 = silu([hR|hC|dist] @ We1 + be1), K=256 via MFMA + dist in acc init ----
    {
        bf16x8 a[8];
        #pragma unroll
        for (int kk = 0; kk < 8; ++kk)
            a[kk] = *(const bf16x8*)&A[w*16 + m][kk*32 + q*8];
        float ed[4];
        #pragma unroll
        for (int rg = 0; rg < 4; ++rg) ed[rg] = edist[w*16 + q*4 + rg];
        #pragma unroll
        for (int nt = 0; nt < 8; ++nt) {
            int n = nt * 16 + m;
            float b0 = be1[n], wr = We1r[n];
            f32x4 c;
            #pragma unroll
            for (int rg = 0; rg < 4; ++rg) c[rg] = fmaf(ed[rg], wr, b0);
            #pragma unroll
            for (int kk = 0; kk < 8; ++kk) {
                bf16x8 b = *(const bf16x8*)&We1F[((nt*8 + kk)*64 + l)*8];
                c = __builtin_amdgcn_mfma_f32_16x16x32_bf16(a[kk], b, c, 0, 0, 0);
            }
            #pragma unroll
            for (int rg = 0; rg < 4; ++rg)
                T[w*16 + q*4 + rg][n] = f2bf(silu_f(c[rg]));
        }
    }

    // ---- layer 2: msg = silu(t1 @ We2 + be2), K=128; scatter to agg; msg bf16 -> A ----
    {
        bf16x8 a[4];
        #pragma unroll
        for (int kk = 0; kk < 4; ++kk)
            a[kk] = *(const bf16x8*)&T[w*16 + m][kk*32 + q*8];
        int rw[4];
        #pragma unroll
        for (int rg = 0; rg < 4; ++rg) rw[rg] = erow[w*16 + q*4 + rg];
        #pragma unroll
        for (int nt = 0; nt < 8; ++nt) {
            int n = nt * 16 + m;
            float b0 = be2[n];
            f32x4 c = { b0, b0, b0, b0 };
            #pragma unroll
            for (int kk = 0; kk < 4; ++kk) {
                bf16x8 b = *(const bf16x8*)&We2F[((nt*4 + kk)*64 + l)*8];
                c = __builtin_amdgcn_mfma_f32_16x16x32_bf16(a[kk], b, c, 0, 0, 0);
            }
            #pragma unroll
            for (int rg = 0; rg < 4; ++rg) {
                float mv = silu_f(c[rg]);
                atomicAdd(&agg[(size_t)rw[rg] * D + n], mv);
                A[w*16 + q*4 + rg][n] = f2bf(mv);
            }
        }
    }

    // ---- coord layer 1: t2 = silu(msg @ Wc1 + bc1), K=128 -> T ----
    {
        bf16x8 a[4];
        #pragma unroll
        for (int kk = 0; kk < 4; ++kk)
            a[kk] = *(const bf16x8*)&A[w*16 + m][kk*32 + q*8];
        #pragma unroll
        for (int nt = 0; nt < 8; ++nt) {
            int n = nt * 16 + m;
            float b0 = bc1[n];
            f32x4 c = { b0, b0, b0, b0 };
            #pragma unroll
            for (int kk = 0; kk < 4; ++kk) {
                bf16x8 b = *(const bf16x8*)&Wc1F[((nt*4 + kk)*64 + l)*8];
                c = __builtin_amdgcn_mfma_f32_16x16x32_bf16(a[kk], b, c, 0, 0, 0);
            }
            #pragma unroll
            for (int rg = 0; rg < 4; ++rg)
                T[w*16 + q*4 + rg][n] = f2bf(silu_f(c[rg]));
        }
    }

    // ---- coord layer 2: w_e = clip(t2 . Wc2); pos scatter (4 lanes/edge) ----
    {
        int e = tid >> 2;           // wave w covers e = w*16 .. w*16+15 (own rows)
        int l4 = tid & 3;
        float p = 0.f;
        #pragma unroll
        for (int i = 0; i < 8; ++i) {
            int k = l4 * 32 + i * 4;
            u16x4 tv = *(const u16x4*)&T[e][k];
            float4 wv = *(const float4*)&Wc2[k];
            p += bf2f(tv.x)*wv.x + bf2f(tv.y)*wv.y + bf2f(tv.z)*wv.z + bf2f(tv.w)*wv.w;
        }
        p += __shfl_xor(p, 1);
        p += __shfl_xor(p, 2);
        if (l4 == 0 && (e0 + e) < E) {
            float cw = fminf(1.0f, fmaxf(-1.0f, p));
            float s = cw / edist[e];
            int r = erow[e];
            atomicAdd(&pos_out[r*3+0], ediff[e][0] * s);
            atomicAdd(&pos_out[r*3+1], ediff[e][1] * s);
            atomicAdd(&pos_out[r*3+2], ediff[e][2] * s);
        }
    }
}

// ---------------- node kernel: MFMA, h_out = h + MLP([h|agg]) ----------------
__global__ __launch_bounds__(256, 3) void egnn_node_mfma(
    const float* __restrict__ h,
    const u16* __restrict__ Wn1F, const float* __restrict__ bn1,
    const u16* __restrict__ Wn2F, const float* __restrict__ bn2,
    float* __restrict__ out, int N)
{
    __shared__ u16 A[64][264];
    __shared__ u16 T[64][136];

    const int tid = threadIdx.x;
    const int w = tid >> 6, l = tid & 63;
    const int q = l >> 4, m = l & 15;
    const int n0 = blockIdx.x * 64;

    // gather [h | agg] -> bf16 LDS (agg lives in out rows, read before overwrite)
    #pragma unroll
    for (int p = 0; p < 16; ++p) {
        int nl = p * 4 + w;
        int node = n0 + nl; if (node >= N) node = N - 1;
        int f0 = (l & 31) * 4;
        const float* src = (l < 32) ? (h + (size_t)node * D + f0)
                                    : (out + (size_t)node * D + f0);
        float4 v = *(const float4*)src;
        u16x4 b; b.x = f2bf(v.x); b.y = f2bf(v.y); b.z = f2bf(v.z); b.w = f2bf(v.w);
        *(u16x4*)&A[nl][(l >> 5) * 128 + f0] = b;
    }
    __syncthreads();   // all agg reads complete before any out overwrite

    // ---- node layer 1: t1 = silu([h|agg] @ Wn1 + bn1), K=256 ----
    {
        bf16x8 a[8];
        #pragma unroll
        for (int kk = 0; kk < 8; ++kk)
            a[kk] = *(const bf16x8*)&A[w*16 + m][kk*32 + q*8];
        #pragma unroll
        for (int nt = 0; nt < 8; ++nt) {
            int n = nt * 16 + m;
            float b0 = bn1[n];
            f32x4 c = { b0, b0, b0, b0 };
            #pragma unroll
            for (int kk = 0; kk < 8; ++kk) {
                bf16x8 b = *(const bf16x8*)&Wn1F[((nt*8 + kk)*64 + l)*8];
                c = __builtin_amdgcn_mfma_f32_16x16x32_bf16(a[kk], b, c, 0, 0, 0);
            }
            #pragma unroll
            for (int rg = 0; rg < 4; ++rg)
                T[w*16 + q*4 + rg][n] = f2bf(silu_f(c[rg]));
        }
    }

    // ---- node layer 2 + residual: out = h + t1 @ Wn2 + bn2, K=128 ----
    {
        bf16x8 a[4];
        #pragma unroll
        for (int kk = 0; kk < 4; ++kk)
            a[kk] = *(const bf16x8*)&T[w*16 + m][kk*32 + q*8];
        #pragma unroll
        for (int nt = 0; nt < 8; ++nt) {
            int n = nt * 16 + m;
            float b0 = bn2[n];
            f32x4 c = { b0, b0, b0, b0 };
            #pragma unroll
            for (int kk = 0; kk < 4; ++kk) {
                bf16x8 b = *(const bf16x8*)&Wn2F[((nt*4 + kk)*64 + l)*8];
                c = __builtin_amdgcn_mfma_f32_16x16x32_bf16(a[kk], b, c, 0, 0, 0);
            }
            #pragma unroll
            for (int rg = 0; rg < 4; ++rg) {
                int node = n0 + w*16 + q*4 + rg;
                if (node < N)
                    out[(size_t)node * D + n] = h[(size_t)node * D + n] + c[rg];
            }
        }
    }
}

extern "C" void kernel_launch(void* const* d_in, const int* in_sizes, int n_in,
                              void* d_out, int out_size, void* d_ws, size_t ws_size,
                              hipStream_t stream)
{
    const float* h   = (const float*)d_in[0];
    const float* pos = (const float*)d_in[1];
    const int*   eidx= (const int*)d_in[2];
    const float* We1 = (const float*)d_in[3];
    const float* be1 = (const float*)d_in[4];
    const float* We2 = (const float*)d_in[5];
    const float* be2 = (const float*)d_in[6];
    const float* Wn1 = (const float*)d_in[7];
    const float* bn1 = (const float*)d_in[8];
    const float* Wn2 = (const float*)d_in[9];
    const float* bn2 = (const float*)d_in[10];
    const float* Wc1 = (const float*)d_in[11];
    const float* bc1 = (const float*)d_in[12];
    const float* Wc2 = (const float*)d_in[13];

    const int N = in_sizes[0] / D;
    const int E = in_sizes[2] / 2;

    float* out     = (float*)d_out;
    float* agg     = out;                       // h-region doubles as agg accumulator
    float* pos_out = out + (size_t)N * D;

    u16* ws = (u16*)d_ws;
    const u16* We1F = ws;
    const u16* We2F = ws + 32768;
    const u16* Wc1F = ws + 49152;
    const u16* Wn1F = ws + 65536;
    const u16* Wn2F = ws + 98304;
    const float* We1r = (const float*)(ws + 114688);

    egnn_init<<<2048, 256, 0, stream>>>(pos, out, N);
    egnn_prep<<<128, 256, 0, stream>>>(We1, We2, Wc1, Wn1, Wn2, ws);
    egnn_edge_mfma<<<(E + 63) / 64, 256, 0, stream>>>(
        h, pos, eidx, We1F, We1r, be1, We2F, be2, Wc1F, bc1, Wc2,
        agg, pos_out, E);
    egnn_node_mfma<<<(N + 63) / 64, 256, 0, stream>>>(
        h, Wn1F, bn1, Wn2F, bn2, out, N);
}

// Round 3
// 642.214 us; speedup vs baseline: 4.6727x; 1.5497x over previous
//
#include <hip/hip_runtime.h>
#include <math.h>
#include <stdint.h>

#define D 128

typedef unsigned short u16;
typedef __attribute__((ext_vector_type(8))) short bf16x8;
typedef __attribute__((ext_vector_type(2))) short bf16x2_t;
typedef __attribute__((ext_vector_type(4))) float f32x4;
typedef __attribute__((ext_vector_type(4))) unsigned short u16x4;

#if __has_builtin(__builtin_amdgcn_global_atomic_fadd_v2bf16)
#define HAVE_PK_BF16 1
#else
#define HAVE_PK_BF16 0
#endif

// ws layout in u16 units:
#define FRAG_WE1 0
#define FRAG_WE2 32768
#define FRAG_WC1 49152
#define FRAG_WN1 65536
#define FRAG_WN2 98304
#define WE1R_OFF 114688   // float[128] = 256 u16
#define AGG_OFF  131072   // bf16 agg[N*D] (BA path only)

__device__ __forceinline__ float silu_f(float x) {
    return x / (1.0f + __expf(-x));
}
__device__ __forceinline__ u16 f2bf(float x) {
    union { float f; unsigned int u; } v; v.f = x;
    unsigned int r = v.u + 0x7fffu + ((v.u >> 16) & 1u);
    return (u16)(r >> 16);
}
__device__ __forceinline__ float bf2f(u16 u) {
    union { unsigned int u; float f; } v; v.u = ((unsigned int)u) << 16; return v.f;
}
__device__ __forceinline__ void pk_add_bf16(u16* addr, float a, float b) {
#if HAVE_PK_BF16
    bf16x2_t v;
    v.x = (short)f2bf(a);
    v.y = (short)f2bf(b);
    __builtin_amdgcn_global_atomic_fadd_v2bf16(
        (__attribute__((address_space(1))) bf16x2_t*)(uintptr_t)addr, v);
#endif
}

// ---------------- init (BA path): zero bf16 agg in ws, copy pos -> pos_out ----------------
__global__ __launch_bounds__(256) void egnn_init_ba(
    const float* __restrict__ pos, float* __restrict__ out,
    uint4* __restrict__ agg4, int N)
{
    int stride = gridDim.x * blockDim.x;
    int nagg = N * D / 8;           // uint4 count over bf16 agg
    int total = nagg + N * 3;
    for (int i = blockIdx.x * blockDim.x + threadIdx.x; i < total; i += stride) {
        if (i < nagg) agg4[i] = make_uint4(0, 0, 0, 0);
        else { int j = i - nagg; out[(size_t)N * D + j] = pos[j]; }
    }
}

// ---------------- init (fallback): zero fp32 agg (= out h region), copy pos ----------------
__global__ __launch_bounds__(256) void egnn_init_f32(
    const float* __restrict__ pos, float* __restrict__ out, int N)
{
    int stride = gridDim.x * blockDim.x;
    int hd = N * D;
    int total = hd + N * 3;
    for (int i = blockIdx.x * blockDim.x + threadIdx.x; i < total; i += stride)
        out[i] = (i < hd) ? 0.0f : pos[i - hd];
}

// ---------------- prep: weights -> fragment-ordered bf16 in ws ----------------
// B-frag order for 16x16x32 MFMA: elem(nt,kk,lane,j) = W[k*128+n],
//   k = kk*32 + (lane>>4)*8 + j,  n = nt*16 + (lane&15)
__global__ __launch_bounds__(256) void egnn_prep(
    const float* __restrict__ We1, const float* __restrict__ We2,
    const float* __restrict__ Wc1, const float* __restrict__ Wn1,
    const float* __restrict__ Wn2, u16* __restrict__ ws)
{
    int i = blockIdx.x * blockDim.x + threadIdx.x;   // grid = 32768 threads
    u16* We1F = ws + FRAG_WE1;
    u16* We2F = ws + FRAG_WE2;
    u16* Wc1F = ws + FRAG_WC1;
    u16* Wn1F = ws + FRAG_WN1;
    u16* Wn2F = ws + FRAG_WN2;
    float* We1r = (float*)(ws + WE1R_OFF);

    if (i < 32768) {   // K=256 matrices
        int j = i & 7, l = (i >> 3) & 63, kk = (i >> 9) & 7, nt = i >> 12;
        int k = kk * 32 + (l >> 4) * 8 + j;
        int n = nt * 16 + (l & 15);
        We1F[i] = f2bf(We1[k * D + n]);
        Wn1F[i] = f2bf(Wn1[k * D + n]);
    }
    if (i < 16384) {   // K=128 matrices
        int j = i & 7, l = (i >> 3) & 63, kk = (i >> 9) & 3, nt = i >> 11;
        int k = kk * 32 + (l >> 4) * 8 + j;
        int n = nt * 16 + (l & 15);
        We2F[i] = f2bf(We2[k * D + n]);
        Wc1F[i] = f2bf(Wc1[k * D + n]);
        Wn2F[i] = f2bf(Wn2[k * D + n]);
    }
    if (i < 128) We1r[i] = We1[256 * D + i];   // dist column of We1
}

// ---------------- edge kernel ----------------
// 64 edges/block, 4 waves. Wave w owns output columns n in [32w, 32w+32)
// (nt = 2w, 2w+1) for ALL 64 edges -> B-fragments register-resident, each
// feeding 4 independent m-tile MFMA chains. Syncs between layers.
template<int BA>
__global__ __launch_bounds__(256, 3) void egnn_edge_mfma(
    const float* __restrict__ h, const float* __restrict__ pos,
    const int* __restrict__ eidx,
    const u16* __restrict__ We1F, const float* __restrict__ We1r,
    const float* __restrict__ be1,
    const u16* __restrict__ We2F, const float* __restrict__ be2,
    const u16* __restrict__ Wc1F, const float* __restrict__ bc1,
    const float* __restrict__ Wc2,
    u16* __restrict__ aggb, float* __restrict__ aggf,
    float* __restrict__ pos_out, int E)
{
    __shared__ u16 A[64][264];   // [h_row|h_col] bf16; later msg in cols 0..127
    __shared__ u16 T[64][136];   // t1, later t2 (coord1 out)
    __shared__ int erow[64], ecol[64];
    __shared__ float ediff[64][3], edist[64];

    const int tid = threadIdx.x;
    const int w = tid >> 6, l = tid & 63;
    const int q = l >> 4, m = l & 15;
    const int e0 = blockIdx.x * 64;

    if (tid < 64) {
        int e = e0 + tid;
        int r = 0, c = 0;
        if (e < E) { r = eidx[e]; c = eidx[E + e]; }
        erow[tid] = r; ecol[tid] = c;
        float dx = pos[r*3+0] - pos[c*3+0];
        float dy = pos[r*3+1] - pos[c*3+1];
        float dz = pos[r*3+2] - pos[c*3+2];
        float dd = fmaxf(sqrtf(dx*dx + dy*dy + dz*dz), 1e-6f);
        ediff[tid][0] = dx; ediff[tid][1] = dy; ediff[tid][2] = dz;
        edist[tid] = dd;
    }
    __syncthreads();

    // gather h[row] | h[col] -> bf16 LDS (512B coalesced per pass)
    #pragma unroll
    for (int p = 0; p < 16; ++p) {
        int el = p * 4 + w;
        int node = (l < 32) ? erow[el] : ecol[el];
        int f0 = (l & 31) * 4;
        float4 v = *(const float4*)(h + (size_t)node * D + f0);
        u16x4 b; b.x = f2bf(v.x); b.y = f2bf(v.y); b.z = f2bf(v.z); b.w = f2bf(v.w);
        *(u16x4*)&A[el][(l >> 5) * 128 + f0] = b;
    }
    __syncthreads();

    // ---- layer 1: t1 = silu([hR|hC|dist] @ We1 + be1), K=256 ----
    {
        bf16x8 Bf[2][8];
        #pragma unroll
        for (int t2 = 0; t2 < 2; ++t2)
            #pragma unroll
            for (int kk = 0; kk < 8; ++kk)
                Bf[t2][kk] = *(const bf16x8*)&We1F[(((2*w + t2)*8 + kk)*64 + l)*8];
        float b0[2], wr[2];
        #pragma unroll
        for (int t2 = 0; t2 < 2; ++t2) {
            int n = (2*w + t2)*16 + m;
            b0[t2] = be1[n]; wr[t2] = We1r[n];
        }
        #pragma unroll
        for (int mt = 0; mt < 4; ++mt) {
            bf16x8 a[8];
            #pragma unroll
            for (int kk = 0; kk < 8; ++kk)
                a[kk] = *(const bf16x8*)&A[mt*16 + m][kk*32 + q*8];
            float ed[4];
            #pragma unroll
            for (int rg = 0; rg < 4; ++rg) ed[rg] = edist[mt*16 + q*4 + rg];
            #pragma unroll
            for (int t2 = 0; t2 < 2; ++t2) {
                f32x4 c;
                #pragma unroll
                for (int rg = 0; rg < 4; ++rg) c[rg] = fmaf(ed[rg], wr[t2], b0[t2]);
                #pragma unroll
                for (int kk = 0; kk < 8; ++kk)
                    c = __builtin_amdgcn_mfma_f32_16x16x32_bf16(a[kk], Bf[t2][kk], c, 0, 0, 0);
                int n = (2*w + t2)*16 + m;
                #pragma unroll
                for (int rg = 0; rg < 4; ++rg)
                    T[mt*16 + q*4 + rg][n] = f2bf(silu_f(c[rg]));
            }
        }
    }
    __syncthreads();

    // ---- layer 2: msg = silu(t1 @ We2 + be2), K=128; scatter to agg; msg -> A ----
    {
        bf16x8 Bf[2][4];
        #pragma unroll
        for (int t2 = 0; t2 < 2; ++t2)
            #pragma unroll
            for (int kk = 0; kk < 4; ++kk)
                Bf[t2][kk] = *(const bf16x8*)&We2F[(((2*w + t2)*4 + kk)*64 + l)*8];
        float b0[2];
        #pragma unroll
        for (int t2 = 0; t2 < 2; ++t2) b0[t2] = be2[(2*w + t2)*16 + m];
        #pragma unroll
        for (int mt = 0; mt < 4; ++mt) {
            bf16x8 a[4];
            #pragma unroll
            for (int kk = 0; kk < 4; ++kk)
                a[kk] = *(const bf16x8*)&T[mt*16 + m][kk*32 + q*8];
            const int rowbase = mt*16 + q*4;
            #pragma unroll
            for (int t2 = 0; t2 < 2; ++t2) {
                f32x4 c = { b0[t2], b0[t2], b0[t2], b0[t2] };
                #pragma unroll
                for (int kk = 0; kk < 4; ++kk)
                    c = __builtin_amdgcn_mfma_f32_16x16x32_bf16(a[kk], Bf[t2][kk], c, 0, 0, 0);
                int n = (2*w + t2)*16 + m;
                #pragma unroll
                for (int rg = 0; rg < 4; ++rg) {
                    float mv = silu_f(c[rg]);
                    A[rowbase + rg][n] = f2bf(mv);
                    if (BA) {
                        float mo = __shfl_xor(mv, 1);
                        if ((m & 1) == 0 && (e0 + rowbase + rg) < E) {
                            int r = erow[rowbase + rg];
                            pk_add_bf16(&aggb[(size_t)r * D + n], mv, mo);
                        }
                    } else {
                        if ((e0 + rowbase + rg) < E) {
                            int r = erow[rowbase + rg];
                            atomicAdd(&aggf[(size_t)r * D + n], mv);
                        }
                    }
                }
            }
        }
    }
    __syncthreads();

    // ---- coord layer 1: t2 = silu(msg @ Wc1 + bc1), K=128 -> T ----
    {
        bf16x8 Bf[2][4];
        #pragma unroll
        for (int t2 = 0; t2 < 2; ++t2)
            #pragma unroll
            for (int kk = 0; kk < 4; ++kk)
                Bf[t2][kk] = *(const bf16x8*)&Wc1F[(((2*w + t2)*4 + kk)*64 + l)*8];
        float b0[2];
        #pragma unroll
        for (int t2 = 0; t2 < 2; ++t2) b0[t2] = bc1[(2*w + t2)*16 + m];
        #pragma unroll
        for (int mt = 0; mt < 4; ++mt) {
            bf16x8 a[4];
            #pragma unroll
            for (int kk = 0; kk < 4; ++kk)
                a[kk] = *(const bf16x8*)&A[mt*16 + m][kk*32 + q*8];
            #pragma unroll
            for (int t2 = 0; t2 < 2; ++t2) {
                f32x4 c = { b0[t2], b0[t2], b0[t2], b0[t2] };
                #pragma unroll
                for (int kk = 0; kk < 4; ++kk)
                    c = __builtin_amdgcn_mfma_f32_16x16x32_bf16(a[kk], Bf[t2][kk], c, 0, 0, 0);
                int n = (2*w + t2)*16 + m;
                #pragma unroll
                for (int rg = 0; rg < 4; ++rg)
                    T[mt*16 + q*4 + rg][n] = f2bf(silu_f(c[rg]));
            }
        }
    }
    __syncthreads();

    // ---- coord layer 2: w_e = clip(t2 . Wc2, -1, 1); pos scatter ----
    {
        int e = tid >> 2;
        int l4 = tid & 3;
        float p = 0.f;
        #pragma unroll
        for (int i = 0; i < 8; ++i) {
            int k = l4 * 32 + i * 4;
            u16x4 tv = *(const u16x4*)&T[e][k];
            float4 wv = *(const float4*)&Wc2[k];
            p += bf2f(tv.x)*wv.x + bf2f(tv.y)*wv.y + bf2f(tv.z)*wv.z + bf2f(tv.w)*wv.w;
        }
        p += __shfl_xor(p, 1);
        p += __shfl_xor(p, 2);
        if (l4 == 0 && (e0 + e) < E) {
            float cw = fminf(1.0f, fmaxf(-1.0f, p));
            float s = cw / edist[e];
            int r = erow[e];
            atomicAdd(&pos_out[r*3+0], ediff[e][0] * s);
            atomicAdd(&pos_out[r*3+1], ediff[e][1] * s);
            atomicAdd(&pos_out[r*3+2], ediff[e][2] * s);
        }
    }
}

// ---------------- node kernel: h_out = h + MLP([h|agg]) ----------------
template<int BA>
__global__ __launch_bounds__(256, 3) void egnn_node_mfma(
    const float* __restrict__ h,
    const u16* __restrict__ aggb, const float* __restrict__ aggf,
    const u16* __restrict__ Wn1F, const float* __restrict__ bn1,
    const u16* __restrict__ Wn2F, const float* __restrict__ bn2,
    float* __restrict__ out, int N)
{
    __shared__ u16 A[64][264];
    __shared__ u16 T[64][136];

    const int tid = threadIdx.x;
    const int w = tid >> 6, l = tid & 63;
    const int q = l >> 4, m = l & 15;
    const int n0 = blockIdx.x * 64;

    // gather [h | agg] -> bf16 LDS
    #pragma unroll
    for (int p = 0; p < 16; ++p) {
        int nl = p * 4 + w;
        int node = n0 + nl; if (node >= N) node = N - 1;
        int f0 = (l & 31) * 4;
        if (l < 32) {
            float4 v = *(const float4*)(h + (size_t)node * D + f0);
            u16x4 b; b.x = f2bf(v.x); b.y = f2bf(v.y); b.z = f2bf(v.z); b.w = f2bf(v.w);
            *(u16x4*)&A[nl][f0] = b;
        } else if (BA) {
            u16x4 v = *(const u16x4*)&aggb[(size_t)node * D + f0];
            *(u16x4*)&A[nl][128 + f0] = v;
        } else {
            float4 v = *(const float4*)(aggf + (size_t)node * D + f0);
            u16x4 b; b.x = f2bf(v.x); b.y = f2bf(v.y); b.z = f2bf(v.z); b.w = f2bf(v.w);
            *(u16x4*)&A[nl][128 + f0] = b;
        }
    }
    __syncthreads();

    // ---- node layer 1: t1 = silu([h|agg] @ Wn1 + bn1), K=256 ----
    {
        bf16x8 Bf[2][8];
        #pragma unroll
        for (int t2 = 0; t2 < 2; ++t2)
            #pragma unroll
            for (int kk = 0; kk < 8; ++kk)
                Bf[t2][kk] = *(const bf16x8*)&Wn1F[(((2*w + t2)*8 + kk)*64 + l)*8];
        float b0[2];
        #pragma unroll
        for (int t2 = 0; t2 < 2; ++t2) b0[t2] = bn1[(2*w + t2)*16 + m];
        #pragma unroll
        for (int mt = 0; mt < 4; ++mt) {
            bf16x8 a[8];
            #pragma unroll
            for (int kk = 0; kk < 8; ++kk)
                a[kk] = *(const bf16x8*)&A[mt*16 + m][kk*32 + q*8];
            #pragma unroll
            for (int t2 = 0; t2 < 2; ++t2) {
                f32x4 c = { b0[t2], b0[t2], b0[t2], b0[t2] };
                #pragma unroll
                for (int kk = 0; kk < 8; ++kk)
                    c = __builtin_amdgcn_mfma_f32_16x16x32_bf16(a[kk], Bf[t2][kk], c, 0, 0, 0);
                int n = (2*w + t2)*16 + m;
                #pragma unroll
                for (int rg = 0; rg < 4; ++rg)
                    T[mt*16 + q*4 + rg][n] = f2bf(silu_f(c[rg]));
            }
        }
    }
    __syncthreads();

    // ---- node layer 2 + residual: out = h + t1 @ Wn2 + bn2, K=128 ----
    {
        bf16x8 Bf[2][4];
        #pragma unroll
        for (int t2 = 0; t2 < 2; ++t2)
            #pragma unroll
            for (int kk = 0; kk < 4; ++kk)
                Bf[t2][kk] = *(const bf16x8*)&Wn2F[(((2*w + t2)*4 + kk)*64 + l)*8];
        float b0[2];
        #pragma unroll
        for (int t2 = 0; t2 < 2; ++t2) b0[t2] = bn2[(2*w + t2)*16 + m];
        #pragma unroll
        for (int mt = 0; mt < 4; ++mt) {
            bf16x8 a[4];
            #pragma unroll
            for (int kk = 0; kk < 4; ++kk)
                a[kk] = *(const bf16x8*)&T[mt*16 + m][kk*32 + q*8];
            #pragma unroll
            for (int t2 = 0; t2 < 2; ++t2) {
                f32x4 c = { b0[t2], b0[t2], b0[t2], b0[t2] };
                #pragma unroll
                for (int kk = 0; kk < 4; ++kk)
                    c = __builtin_amdgcn_mfma_f32_16x16x32_bf16(a[kk], Bf[t2][kk], c, 0, 0, 0);
                int n = (2*w + t2)*16 + m;
                #pragma unroll
                for (int rg = 0; rg < 4; ++rg) {
                    int node = n0 + mt*16 + q*4 + rg;
                    if (node < N)
                        out[(size_t)node * D + n] = h[(size_t)node * D + n] + c[rg];
                }
            }
        }
    }
}

extern "C" void kernel_launch(void* const* d_in, const int* in_sizes, int n_in,
                              void* d_out, int out_size, void* d_ws, size_t ws_size,
                              hipStream_t stream)
{
    const float* h   = (const float*)d_in[0];
    const float* pos = (const float*)d_in[1];
    const int*   eidx= (const int*)d_in[2];
    const float* We1 = (const float*)d_in[3];
    const float* be1 = (const float*)d_in[4];
    const float* We2 = (const float*)d_in[5];
    const float* be2 = (const float*)d_in[6];
    const float* Wn1 = (const float*)d_in[7];
    const float* bn1 = (const float*)d_in[8];
    const float* Wn2 = (const float*)d_in[9];
    const float* bn2 = (const float*)d_in[10];
    const float* Wc1 = (const float*)d_in[11];
    const float* bc1 = (const float*)d_in[12];
    const float* Wc2 = (const float*)d_in[13];

    const int N = in_sizes[0] / D;
    const int E = in_sizes[2] / 2;

    float* out     = (float*)d_out;
    float* pos_out = out + (size_t)N * D;

    u16* ws = (u16*)d_ws;
    const u16* We1F = ws + FRAG_WE1;
    const u16* We2F = ws + FRAG_WE2;
    const u16* Wc1F = ws + FRAG_WC1;
    const u16* Wn1F = ws + FRAG_WN1;
    const u16* Wn2F = ws + FRAG_WN2;
    const float* We1r = (const float*)(ws + WE1R_OFF);

    u16*   aggb = ws + AGG_OFF;
    float* aggf = out;   // fallback: agg fp32 in out h-region

    const size_t need = (size_t)AGG_OFF * 2 + (size_t)N * D * 2;
    const bool ba = HAVE_PK_BF16 && ws_size >= need;

    egnn_prep<<<128, 256, 0, stream>>>(We1, We2, Wc1, Wn1, Wn2, ws);
    if (ba) {
        egnn_init_ba<<<2048, 256, 0, stream>>>(pos, out, (uint4*)aggb, N);
        egnn_edge_mfma<1><<<(E + 63) / 64, 256, 0, stream>>>(
            h, pos, eidx, We1F, We1r, be1, We2F, be2, Wc1F, bc1, Wc2,
            aggb, aggf, pos_out, E);
        egnn_node_mfma<1><<<(N + 63) / 64, 256, 0, stream>>>(
            h, aggb, aggf, Wn1F, bn1, Wn2F, bn2, out, N);
    } else {
        egnn_init_f32<<<2048, 256, 0, stream>>>(pos, out, N);
        egnn_edge_mfma<0><<<(E + 63) / 64, 256, 0, stream>>>(
            h, pos, eidx, We1F, We1r, be1, We2F, be2, Wc1F, bc1, Wc2,
            aggb, aggf, pos_out, E);
        egnn_node_mfma<0><<<(N + 63) / 64, 256, 0, stream>>>(
            h, aggb, aggf, Wn1F, bn1, Wn2F, bn2, out, N);
    }
}

// Round 4
// 533.639 us; speedup vs baseline: 5.6234x; 1.2035x over previous
//
#include <hip/hip_runtime.h>
#include <hip/hip_bf16.h>
#include <math.h>
#include <stdint.h>

#define D 128

typedef unsigned short u16;
typedef __attribute__((ext_vector_type(8))) short bf16x8;
typedef __attribute__((ext_vector_type(4))) float f32x4;
typedef __attribute__((ext_vector_type(4))) unsigned short u16x4;

// ws layout in u16 units:
#define FRAG_WE1 0
#define FRAG_WE2 32768
#define FRAG_WC1 49152
#define FRAG_WN1 65536
#define FRAG_WN2 98304
#define WE1R_OFF 114688   // float[128] = 256 u16
#define AGG_OFF  131072   // bf16 agg[N*D] (BA path)

__device__ __forceinline__ float silu_f(float x) {
    return x / (1.0f + __expf(-x));
}
__device__ __forceinline__ u16 f2bf(float x) {
    union { float f; unsigned int u; } v; v.f = x;
    unsigned int r = v.u + 0x7fffu + ((v.u >> 16) & 1u);
    return (u16)(r >> 16);
}
__device__ __forceinline__ float bf2f(u16 u) {
    union { unsigned int u; float f; } v; v.u = ((unsigned int)u) << 16; return v.f;
}
__device__ __forceinline__ unsigned pk2bf(float a, float b) {
    union { __hip_bfloat162 v; unsigned u; } u;
    u.v = __float22bfloat162_rn(make_float2(a, b));
    return u.u;
}
// packed bf16 atomic add — raw asm (the clang builtin is gone on ROCm 7)
__device__ __forceinline__ void pk_agg_add(u16* addr, unsigned packed) {
    asm volatile("global_atomic_pk_add_bf16 %0, %1, off"
                 :: "v"(addr), "v"(packed) : "memory");
}

// ---------------- init (BA): zero bf16 agg in ws, copy pos -> pos_out ----------------
__global__ __launch_bounds__(256) void egnn_init_ba(
    const float* __restrict__ pos, float* __restrict__ out,
    uint4* __restrict__ agg4, int N)
{
    int stride = gridDim.x * blockDim.x;
    int nagg = N * D / 8;
    int total = nagg + N * 3;
    for (int i = blockIdx.x * blockDim.x + threadIdx.x; i < total; i += stride) {
        if (i < nagg) agg4[i] = make_uint4(0, 0, 0, 0);
        else { int j = i - nagg; out[(size_t)N * D + j] = pos[j]; }
    }
}

// ---------------- init (fallback): zero fp32 agg (= out h region), copy pos ----------------
__global__ __launch_bounds__(256) void egnn_init_f32(
    const float* __restrict__ pos, float* __restrict__ out, int N)
{
    int stride = gridDim.x * blockDim.x;
    int hd = N * D;
    int total = hd + N * 3;
    for (int i = blockIdx.x * blockDim.x + threadIdx.x; i < total; i += stride)
        out[i] = (i < hd) ? 0.0f : pos[i - hd];
}

// ---------------- prep: weights -> fragment-ordered bf16 ----------------
// B-frag: elem(nt,kk,lane,j) = W[k*128+n], k = kk*32+(lane>>4)*8+j, n = nt*16+(lane&15)
__global__ __launch_bounds__(256) void egnn_prep(
    const float* __restrict__ We1, const float* __restrict__ We2,
    const float* __restrict__ Wc1, const float* __restrict__ Wn1,
    const float* __restrict__ Wn2, u16* __restrict__ ws)
{
    int i = blockIdx.x * blockDim.x + threadIdx.x;   // 32768 threads
    u16* We1F = ws + FRAG_WE1;
    u16* We2F = ws + FRAG_WE2;
    u16* Wc1F = ws + FRAG_WC1;
    u16* Wn1F = ws + FRAG_WN1;
    u16* Wn2F = ws + FRAG_WN2;
    float* We1r = (float*)(ws + WE1R_OFF);

    if (i < 32768) {
        int j = i & 7, l = (i >> 3) & 63, kk = (i >> 9) & 7, nt = i >> 12;
        int k = kk * 32 + (l >> 4) * 8 + j;
        int n = nt * 16 + (l & 15);
        We1F[i] = f2bf(We1[k * D + n]);
        Wn1F[i] = f2bf(Wn1[k * D + n]);
    }
    if (i < 16384) {
        int j = i & 7, l = (i >> 3) & 63, kk = (i >> 9) & 3, nt = i >> 11;
        int k = kk * 32 + (l >> 4) * 8 + j;
        int n = nt * 16 + (l & 15);
        We2F[i] = f2bf(We2[k * D + n]);
        Wc1F[i] = f2bf(Wc1[k * D + n]);
        Wn2F[i] = f2bf(Wn2[k * D + n]);
    }
    if (i < 128) We1r[i] = We1[256 * D + i];
}

// ---------------- edge kernel ----------------
// 64 edges/block, 4 waves; wave w owns cols [32w,32w+32) for all rows.
// agg scatter deferred to kernel tail (no barrier behind it -> no forced drain).
template<int BA>
__global__ __launch_bounds__(256, 3) void egnn_edge_mfma(
    const float* __restrict__ h, const float* __restrict__ pos,
    const int* __restrict__ eidx,
    const u16* __restrict__ We1F, const float* __restrict__ We1r,
    const float* __restrict__ be1,
    const u16* __restrict__ We2F, const float* __restrict__ be2,
    const u16* __restrict__ Wc1F, const float* __restrict__ bc1,
    const float* __restrict__ Wc2,
    u16* __restrict__ aggb, float* __restrict__ aggf,
    float* __restrict__ pos_out, int E)
{
    __shared__ u16 A[64][264];   // [h_row|h_col] bf16; after layer2: msg in cols 0..127
    __shared__ u16 T[64][136];
    __shared__ int erow[64], ecol[64];
    __shared__ float ediff[64][3], edist[64];

    const int tid = threadIdx.x;
    const int w = tid >> 6, l = tid & 63;
    const int q = l >> 4, m = l & 15;
    const int e0 = blockIdx.x * 64;

    if (tid < 64) {
        int e = e0 + tid;
        int r = 0, c = 0;
        if (e < E) { r = eidx[e]; c = eidx[E + e]; }
        erow[tid] = r; ecol[tid] = c;
        float dx = pos[r*3+0] - pos[c*3+0];
        float dy = pos[r*3+1] - pos[c*3+1];
        float dz = pos[r*3+2] - pos[c*3+2];
        float dd = fmaxf(sqrtf(dx*dx + dy*dy + dz*dz), 1e-6f);
        ediff[tid][0] = dx; ediff[tid][1] = dy; ediff[tid][2] = dz;
        edist[tid] = dd;
    }
    __syncthreads();

    // hoist layer-1 B-frags: their L2 latency overlaps the gather below
    bf16x8 B1[2][8];
    #pragma unroll
    for (int t2 = 0; t2 < 2; ++t2)
        #pragma unroll
        for (int kk = 0; kk < 8; ++kk)
            B1[t2][kk] = *(const bf16x8*)&We1F[(((2*w + t2)*8 + kk)*64 + l)*8];
    float b1_[2], wr1[2];
    #pragma unroll
    for (int t2 = 0; t2 < 2; ++t2) {
        int n = (2*w + t2)*16 + m;
        b1_[t2] = be1[n]; wr1[t2] = We1r[n];
    }

    // gather h[row] | h[col] -> bf16 LDS (512B coalesced per pass)
    #pragma unroll
    for (int p = 0; p < 16; ++p) {
        int el = p * 4 + w;
        int node = (l < 32) ? erow[el] : ecol[el];
        int f0 = (l & 31) * 4;
        float4 v = *(const float4*)(h + (size_t)node * D + f0);
        uint2 pk; pk.x = pk2bf(v.x, v.y); pk.y = pk2bf(v.z, v.w);
        *(uint2*)&A[el][(l >> 5) * 128 + f0] = pk;
    }
    __syncthreads();

    // ---- layer 1: t1 = silu([hR|hC|dist] @ We1 + be1), K=256 ----
    {
        #pragma unroll
        for (int mt = 0; mt < 4; ++mt) {
            bf16x8 a[8];
            #pragma unroll
            for (int kk = 0; kk < 8; ++kk)
                a[kk] = *(const bf16x8*)&A[mt*16 + m][kk*32 + q*8];
            float ed[4];
            #pragma unroll
            for (int rg = 0; rg < 4; ++rg) ed[rg] = edist[mt*16 + q*4 + rg];
            #pragma unroll
            for (int t2 = 0; t2 < 2; ++t2) {
                f32x4 c;
                #pragma unroll
                for (int rg = 0; rg < 4; ++rg) c[rg] = fmaf(ed[rg], wr1[t2], b1_[t2]);
                #pragma unroll
                for (int kk = 0; kk < 8; ++kk)
                    c = __builtin_amdgcn_mfma_f32_16x16x32_bf16(a[kk], B1[t2][kk], c, 0, 0, 0);
                int n = (2*w + t2)*16 + m;
                #pragma unroll
                for (int rg = 0; rg < 4; ++rg)
                    T[mt*16 + q*4 + rg][n] = f2bf(silu_f(c[rg]));
            }
        }
    }
    __syncthreads();

    // ---- layer 2: msg = silu(t1 @ We2 + be2) -> A (LDS only; scatter deferred) ----
    {
        bf16x8 Bf[2][4];
        #pragma unroll
        for (int t2 = 0; t2 < 2; ++t2)
            #pragma unroll
            for (int kk = 0; kk < 4; ++kk)
                Bf[t2][kk] = *(const bf16x8*)&We2F[(((2*w + t2)*4 + kk)*64 + l)*8];
        float b0[2];
        #pragma unroll
        for (int t2 = 0; t2 < 2; ++t2) b0[t2] = be2[(2*w + t2)*16 + m];
        #pragma unroll
        for (int mt = 0; mt < 4; ++mt) {
            bf16x8 a[4];
            #pragma unroll
            for (int kk = 0; kk < 4; ++kk)
                a[kk] = *(const bf16x8*)&T[mt*16 + m][kk*32 + q*8];
            const int rowbase = mt*16 + q*4;
            #pragma unroll
            for (int t2 = 0; t2 < 2; ++t2) {
                f32x4 c = { b0[t2], b0[t2], b0[t2], b0[t2] };
                #pragma unroll
                for (int kk = 0; kk < 4; ++kk)
                    c = __builtin_amdgcn_mfma_f32_16x16x32_bf16(a[kk], Bf[t2][kk], c, 0, 0, 0);
                int n = (2*w + t2)*16 + m;
                #pragma unroll
                for (int rg = 0; rg < 4; ++rg)
                    A[rowbase + rg][n] = f2bf(silu_f(c[rg]));
            }
        }
    }
    __syncthreads();

    // ---- coord layer 1: t2 = silu(msg @ Wc1 + bc1) -> T ----
    {
        bf16x8 Bf[2][4];
        #pragma unroll
        for (int t2 = 0; t2 < 2; ++t2)
            #pragma unroll
            for (int kk = 0; kk < 4; ++kk)
                Bf[t2][kk] = *(const bf16x8*)&Wc1F[(((2*w + t2)*4 + kk)*64 + l)*8];
        float b0[2];
        #pragma unroll
        for (int t2 = 0; t2 < 2; ++t2) b0[t2] = bc1[(2*w + t2)*16 + m];
        #pragma unroll
        for (int mt = 0; mt < 4; ++mt) {
            bf16x8 a[4];
            #pragma unroll
            for (int kk = 0; kk < 4; ++kk)
                a[kk] = *(const bf16x8*)&A[mt*16 + m][kk*32 + q*8];
            #pragma unroll
            for (int t2 = 0; t2 < 2; ++t2) {
                f32x4 c = { b0[t2], b0[t2], b0[t2], b0[t2] };
                #pragma unroll
                for (int kk = 0; kk < 4; ++kk)
                    c = __builtin_amdgcn_mfma_f32_16x16x32_bf16(a[kk], Bf[t2][kk], c, 0, 0, 0);
                int n = (2*w + t2)*16 + m;
                #pragma unroll
                for (int rg = 0; rg < 4; ++rg)
                    T[mt*16 + q*4 + rg][n] = f2bf(silu_f(c[rg]));
            }
        }
    }
    __syncthreads();

    // ---- coord layer 2: w_e = clip(t2 . Wc2, -1, 1); pos scatter ----
    {
        int e = tid >> 2;
        int l4 = tid & 3;
        float p = 0.f;
        #pragma unroll
        for (int i = 0; i < 8; ++i) {
            int k = l4 * 32 + i * 4;
            u16x4 tv = *(const u16x4*)&T[e][k];
            float4 wv = *(const float4*)&Wc2[k];
            p += bf2f(tv.x)*wv.x + bf2f(tv.y)*wv.y + bf2f(tv.z)*wv.z + bf2f(tv.w)*wv.w;
        }
        p += __shfl_xor(p, 1);
        p += __shfl_xor(p, 2);
        if (l4 == 0 && (e0 + e) < E) {
            float cw = fminf(1.0f, fmaxf(-1.0f, p));
            float s = cw / edist[e];
            int r = erow[e];
            atomicAdd(&pos_out[r*3+0], ediff[e][0] * s);
            atomicAdd(&pos_out[r*3+1], ediff[e][1] * s);
            atomicAdd(&pos_out[r*3+2], ediff[e][2] * s);
        }
    }

    // ---- tail: agg scatter from LDS msg — issued last, drains at kernel retire ----
    if (BA) {
        #pragma unroll
        for (int e2 = 0; e2 < 16; ++e2) {
            int e = w * 16 + e2;
            if ((e0 + e) < E) {
                int r = erow[e];
                unsigned pk = *(const unsigned*)&A[e][l * 2];   // already bf16 pair
                pk_agg_add(&aggb[(size_t)r * D + l * 2], pk);
            }
        }
    } else {
        #pragma unroll
        for (int e2 = 0; e2 < 16; ++e2) {
            int e = w * 16 + e2;
            if ((e0 + e) < E) {
                int r = erow[e];
                atomicAdd(&aggf[(size_t)r * D + l],      bf2f(A[e][l]));
                atomicAdd(&aggf[(size_t)r * D + l + 64], bf2f(A[e][l + 64]));
            }
        }
    }
}

// ---------------- node kernel: h_out = h + MLP([h|agg]) ----------------
template<int BA>
__global__ __launch_bounds__(256, 3) void egnn_node_mfma(
    const float* __restrict__ h,
    const u16* __restrict__ aggb, const float* __restrict__ aggf,
    const u16* __restrict__ Wn1F, const float* __restrict__ bn1,
    const u16* __restrict__ Wn2F, const float* __restrict__ bn2,
    float* __restrict__ out, int N)
{
    __shared__ u16 A[64][264];
    __shared__ u16 T[64][136];

    const int tid = threadIdx.x;
    const int w = tid >> 6, l = tid & 63;
    const int q = l >> 4, m = l & 15;
    const int n0 = blockIdx.x * 64;

    bf16x8 B1[2][8];
    #pragma unroll
    for (int t2 = 0; t2 < 2; ++t2)
        #pragma unroll
        for (int kk = 0; kk < 8; ++kk)
            B1[t2][kk] = *(const bf16x8*)&Wn1F[(((2*w + t2)*8 + kk)*64 + l)*8];

    // gather [h | agg] -> bf16 LDS
    #pragma unroll
    for (int p = 0; p < 16; ++p) {
        int nl = p * 4 + w;
        int node = n0 + nl; if (node >= N) node = N - 1;
        int f0 = (l & 31) * 4;
        if (l < 32) {
            float4 v = *(const float4*)(h + (size_t)node * D + f0);
            uint2 pk; pk.x = pk2bf(v.x, v.y); pk.y = pk2bf(v.z, v.w);
            *(uint2*)&A[nl][f0] = pk;
        } else if (BA) {
            u16x4 v = *(const u16x4*)&aggb[(size_t)node * D + f0];
            *(u16x4*)&A[nl][128 + f0] = v;
        } else {
            float4 v = *(const float4*)(aggf + (size_t)node * D + f0);
            uint2 pk; pk.x = pk2bf(v.x, v.y); pk.y = pk2bf(v.z, v.w);
            *(uint2*)&A[nl][128 + f0] = pk;
        }
    }
    __syncthreads();

    // ---- node layer 1 ----
    {
        float b0[2];
        #pragma unroll
        for (int t2 = 0; t2 < 2; ++t2) b0[t2] = bn1[(2*w + t2)*16 + m];
        #pragma unroll
        for (int mt = 0; mt < 4; ++mt) {
            bf16x8 a[8];
            #pragma unroll
            for (int kk = 0; kk < 8; ++kk)
                a[kk] = *(const bf16x8*)&A[mt*16 + m][kk*32 + q*8];
            #pragma unroll
            for (int t2 = 0; t2 < 2; ++t2) {
                f32x4 c = { b0[t2], b0[t2], b0[t2], b0[t2] };
                #pragma unroll
                for (int kk = 0; kk < 8; ++kk)
                    c = __builtin_amdgcn_mfma_f32_16x16x32_bf16(a[kk], B1[t2][kk], c, 0, 0, 0);
                int n = (2*w + t2)*16 + m;
                #pragma unroll
                for (int rg = 0; rg < 4; ++rg)
                    T[mt*16 + q*4 + rg][n] = f2bf(silu_f(c[rg]));
            }
        }
    }
    __syncthreads();

    // ---- node layer 2 + residual ----
    {
        bf16x8 Bf[2][4];
        #pragma unroll
        for (int t2 = 0; t2 < 2; ++t2)
            #pragma unroll
            for (int kk = 0; kk < 4; ++kk)
                Bf[t2][kk] = *(const bf16x8*)&Wn2F[(((2*w + t2)*4 + kk)*64 + l)*8];
        float b0[2];
        #pragma unroll
        for (int t2 = 0; t2 < 2; ++t2) b0[t2] = bn2[(2*w + t2)*16 + m];
        #pragma unroll
        for (int mt = 0; mt < 4; ++mt) {
            bf16x8 a[4];
            #pragma unroll
            for (int kk = 0; kk < 4; ++kk)
                a[kk] = *(const bf16x8*)&T[mt*16 + m][kk*32 + q*8];
            #pragma unroll
            for (int t2 = 0; t2 < 2; ++t2) {
                f32x4 c = { b0[t2], b0[t2], b0[t2], b0[t2] };
                #pragma unroll
                for (int kk = 0; kk < 4; ++kk)
                    c = __builtin_amdgcn_mfma_f32_16x16x32_bf16(a[kk], Bf[t2][kk], c, 0, 0, 0);
                int n = (2*w + t2)*16 + m;
                #pragma unroll
                for (int rg = 0; rg < 4; ++rg) {
                    int node = n0 + mt*16 + q*4 + rg;
                    if (node < N)
                        out[(size_t)node * D + n] = h[(size_t)node * D + n] + c[rg];
                }
            }
        }
    }
}

extern "C" void kernel_launch(void* const* d_in, const int* in_sizes, int n_in,
                              void* d_out, int out_size, void* d_ws, size_t ws_size,
                              hipStream_t stream)
{
    const float* h   = (const float*)d_in[0];
    const float* pos = (const float*)d_in[1];
    const int*   eidx= (const int*)d_in[2];
    const float* We1 = (const float*)d_in[3];
    const float* be1 = (const float*)d_in[4];
    const float* We2 = (const float*)d_in[5];
    const float* be2 = (const float*)d_in[6];
    const float* Wn1 = (const float*)d_in[7];
    const float* bn1 = (const float*)d_in[8];
    const float* Wn2 = (const float*)d_in[9];
    const float* bn2 = (const float*)d_in[10];
    const float* Wc1 = (const float*)d_in[11];
    const float* bc1 = (const float*)d_in[12];
    const float* Wc2 = (const float*)d_in[13];

    const int N = in_sizes[0] / D;
    const int E = in_sizes[2] / 2;

    float* out     = (float*)d_out;
    float* pos_out = out + (size_t)N * D;

    u16* ws = (u16*)d_ws;
    const u16* We1F = ws + FRAG_WE1;
    const u16* We2F = ws + FRAG_WE2;
    const u16* Wc1F = ws + FRAG_WC1;
    const u16* Wn1F = ws + FRAG_WN1;
    const u16* Wn2F = ws + FRAG_WN2;
    const float* We1r = (const float*)(ws + WE1R_OFF);

    u16*   aggb = ws + AGG_OFF;
    float* aggf = out;   // fallback: fp32 agg in out h-region

    const size_t need = ((size_t)AGG_OFF + (size_t)N * D) * 2;
    const bool ba = ws_size >= need;

    egnn_prep<<<128, 256, 0, stream>>>(We1, We2, Wc1, Wn1, Wn2, ws);
    if (ba) {
        egnn_init_ba<<<2048, 256, 0, stream>>>(pos, out, (uint4*)aggb, N);
        egnn_edge_mfma<1><<<(E + 63) / 64, 256, 0, stream>>>(
            h, pos, eidx, We1F, We1r, be1, We2F, be2, Wc1F, bc1, Wc2,
            aggb, aggf, pos_out, E);
        egnn_node_mfma<1><<<(N + 63) / 64, 256, 0, stream>>>(
            h, aggb, aggf, Wn1F, bn1, Wn2F, bn2, out, N);
    } else {
        egnn_init_f32<<<2048, 256, 0, stream>>>(pos, out, N);
        egnn_edge_mfma<0><<<(E + 63) / 64, 256, 0, stream>>>(
            h, pos, eidx, We1F, We1r, be1, We2F, be2, Wc1F, bc1, Wc2,
            aggb, aggf, pos_out, E);
        egnn_node_mfma<0><<<(N + 63) / 64, 256, 0, stream>>>(
            h, aggb, aggf, Wn1F, bn1, Wn2F, bn2, out, N);
    }
}

// Round 5
// 521.450 us; speedup vs baseline: 5.7548x; 1.0234x over previous
//
#include <hip/hip_runtime.h>
#include <hip/hip_bf16.h>
#include <math.h>
#include <stdint.h>

#define D 128

typedef unsigned short u16;
typedef __attribute__((ext_vector_type(8))) short bf16x8;
typedef __attribute__((ext_vector_type(4))) float f32x4;
typedef __attribute__((ext_vector_type(4))) unsigned short u16x4;

// ws layout in u16 units:
#define FRAG_WE1 0
#define FRAG_WE2 32768
#define FRAG_WC1 49152
#define FRAG_WN1 65536
#define FRAG_WN2 98304
#define WE1R_OFF 114688   // float[128] = 256 u16
#define AGG_OFF  131072   // bf16 agg[N*D] (BA path)

__device__ __forceinline__ float silu_f(float x) {
    return x / (1.0f + __expf(-x));
}
__device__ __forceinline__ u16 f2bf(float x) {
    union { float f; unsigned int u; } v; v.f = x;
    unsigned int r = v.u + 0x7fffu + ((v.u >> 16) & 1u);
    return (u16)(r >> 16);
}
__device__ __forceinline__ float bf2f(u16 u) {
    union { unsigned int u; float f; } v; v.u = ((unsigned int)u) << 16; return v.f;
}
__device__ __forceinline__ unsigned pk2bf(float a, float b) {
    union { __hip_bfloat162 v; unsigned u; } u;
    u.v = __float22bfloat162_rn(make_float2(a, b));
    return u.u;
}
// packed bf16 atomic add — raw asm (clang builtin removed on ROCm 7)
__device__ __forceinline__ void pk_agg_add(u16* addr, unsigned packed) {
    asm volatile("global_atomic_pk_add_bf16 %0, %1, off"
                 :: "v"(addr), "v"(packed) : "memory");
}

// ---------------- init (BA): zero bf16 agg in ws, copy pos -> pos_out ----------------
__global__ __launch_bounds__(256) void egnn_init_ba(
    const float* __restrict__ pos, float* __restrict__ out,
    uint4* __restrict__ agg4, int N)
{
    int stride = gridDim.x * blockDim.x;
    int nagg = N * D / 8;
    int total = nagg + N * 3;
    for (int i = blockIdx.x * blockDim.x + threadIdx.x; i < total; i += stride) {
        if (i < nagg) agg4[i] = make_uint4(0, 0, 0, 0);
        else { int j = i - nagg; out[(size_t)N * D + j] = pos[j]; }
    }
}

// ---------------- init (fallback): zero fp32 agg (= out h region), copy pos ----------------
__global__ __launch_bounds__(256) void egnn_init_f32(
    const float* __restrict__ pos, float* __restrict__ out, int N)
{
    int stride = gridDim.x * blockDim.x;
    int hd = N * D;
    int total = hd + N * 3;
    for (int i = blockIdx.x * blockDim.x + threadIdx.x; i < total; i += stride)
        out[i] = (i < hd) ? 0.0f : pos[i - hd];
}

// ---------------- prep: weights -> fragment-ordered bf16 ----------------
// B-frag: elem(nt,kk,lane,j) = W[k*128+n], k = kk*32+(lane>>4)*8+j, n = nt*16+(lane&15)
__global__ __launch_bounds__(256) void egnn_prep(
    const float* __restrict__ We1, const float* __restrict__ We2,
    const float* __restrict__ Wc1, const float* __restrict__ Wn1,
    const float* __restrict__ Wn2, u16* __restrict__ ws)
{
    int i = blockIdx.x * blockDim.x + threadIdx.x;   // 32768 threads
    u16* We1F = ws + FRAG_WE1;
    u16* We2F = ws + FRAG_WE2;
    u16* Wc1F = ws + FRAG_WC1;
    u16* Wn1F = ws + FRAG_WN1;
    u16* Wn2F = ws + FRAG_WN2;
    float* We1r = (float*)(ws + WE1R_OFF);

    if (i < 32768) {
        int j = i & 7, l = (i >> 3) & 63, kk = (i >> 9) & 7, nt = i >> 12;
        int k = kk * 32 + (l >> 4) * 8 + j;
        int n = nt * 16 + (l & 15);
        We1F[i] = f2bf(We1[k * D + n]);
        Wn1F[i] = f2bf(Wn1[k * D + n]);
    }
    if (i < 16384) {
        int j = i & 7, l = (i >> 3) & 63, kk = (i >> 9) & 3, nt = i >> 11;
        int k = kk * 32 + (l >> 4) * 8 + j;
        int n = nt * 16 + (l & 15);
        We2F[i] = f2bf(We2[k * D + n]);
        Wc1F[i] = f2bf(Wc1[k * D + n]);
        Wn2F[i] = f2bf(Wn2[k * D + n]);
    }
    if (i < 128) We1r[i] = We1[256 * D + i];
}

// ---------------- edge kernel ----------------
// 64 edges/block, 4 waves; wave w owns cols [32w,32w+32).
// LDS overlay: A cols [0,128) = h_row then msg; cols [128,256) = h_col then T.
// L1 outputs held in regs across a barrier (h_col -> T handoff).
template<int BA>
__global__ __launch_bounds__(256, 4) void egnn_edge_mfma(
    const float* __restrict__ h, const float* __restrict__ pos,
    const int* __restrict__ eidx,
    const u16* __restrict__ We1F, const float* __restrict__ We1r,
    const float* __restrict__ be1,
    const u16* __restrict__ We2F, const float* __restrict__ be2,
    const u16* __restrict__ Wc1F, const float* __restrict__ bc1,
    const float* __restrict__ Wc2,
    u16* __restrict__ aggb, float* __restrict__ aggf,
    float* __restrict__ pos_out, int E)
{
    __shared__ u16 A[64][264];
    __shared__ int erow[64], ecol[64];
    __shared__ float ediff[64][3], edist[64];

    const int tid = threadIdx.x;
    const int w = tid >> 6, l = tid & 63;
    const int q = l >> 4, m = l & 15;
    const int e0 = blockIdx.x * 64;

    if (tid < 64) {
        int e = e0 + tid;
        int r = 0, c = 0;
        if (e < E) { r = eidx[e]; c = eidx[E + e]; }
        erow[tid] = r; ecol[tid] = c;
        float dx = pos[r*3+0] - pos[c*3+0];
        float dy = pos[r*3+1] - pos[c*3+1];
        float dz = pos[r*3+2] - pos[c*3+2];
        float dd = fmaxf(sqrtf(dx*dx + dy*dy + dz*dz), 1e-6f);
        ediff[tid][0] = dx; ediff[tid][1] = dy; ediff[tid][2] = dz;
        edist[tid] = dd;
    }
    __syncthreads();

    // hoist layer-1 B-frags (L2 latency overlaps the gather)
    bf16x8 B1[2][8];
    #pragma unroll
    for (int t2 = 0; t2 < 2; ++t2)
        #pragma unroll
        for (int kk = 0; kk < 8; ++kk)
            B1[t2][kk] = *(const bf16x8*)&We1F[(((2*w + t2)*8 + kk)*64 + l)*8];
    float b1_[2], wr1[2];
    #pragma unroll
    for (int t2 = 0; t2 < 2; ++t2) {
        int n = (2*w + t2)*16 + m;
        b1_[t2] = be1[n]; wr1[t2] = We1r[n];
    }

    // gather h[row] | h[col] -> bf16 LDS
    #pragma unroll
    for (int p = 0; p < 16; ++p) {
        int el = p * 4 + w;
        int node = (l < 32) ? erow[el] : ecol[el];
        int f0 = (l & 31) * 4;
        float4 v = *(const float4*)(h + (size_t)node * D + f0);
        uint2 pk; pk.x = pk2bf(v.x, v.y); pk.y = pk2bf(v.z, v.w);
        *(uint2*)&A[el][(l >> 5) * 128 + f0] = pk;
    }
    __syncthreads();

    // ---- layer 1 compute: t1 = silu([hR|hC|dist] @ We1 + be1), hold in regs ----
    unsigned hold[4][2][2];
    #pragma unroll
    for (int mt = 0; mt < 4; ++mt) {
        bf16x8 a[8];
        #pragma unroll
        for (int kk = 0; kk < 8; ++kk)
            a[kk] = *(const bf16x8*)&A[mt*16 + m][kk*32 + q*8];
        float ed[4];
        #pragma unroll
        for (int rg = 0; rg < 4; ++rg) ed[rg] = edist[mt*16 + q*4 + rg];
        #pragma unroll
        for (int t2 = 0; t2 < 2; ++t2) {
            f32x4 c;
            #pragma unroll
            for (int rg = 0; rg < 4; ++rg) c[rg] = fmaf(ed[rg], wr1[t2], b1_[t2]);
            #pragma unroll
            for (int kk = 0; kk < 8; ++kk)
                c = __builtin_amdgcn_mfma_f32_16x16x32_bf16(a[kk], B1[t2][kk], c, 0, 0, 0);
            hold[mt][t2][0] = pk2bf(silu_f(c[0]), silu_f(c[1]));
            hold[mt][t2][1] = pk2bf(silu_f(c[2]), silu_f(c[3]));
        }
    }
    __syncthreads();   // all h_col reads done before T overlay writes

    #pragma unroll
    for (int mt = 0; mt < 4; ++mt)
        #pragma unroll
        for (int t2 = 0; t2 < 2; ++t2) {
            int n = 128 + (2*w + t2)*16 + m;
            int rb = mt*16 + q*4;
            unsigned h0 = hold[mt][t2][0], h1 = hold[mt][t2][1];
            A[rb + 0][n] = (u16)h0;
            A[rb + 1][n] = (u16)(h0 >> 16);
            A[rb + 2][n] = (u16)h1;
            A[rb + 3][n] = (u16)(h1 >> 16);
        }
    __syncthreads();

    // ---- layer 2: msg = silu(t1 @ We2 + be2); T (cols 128+) -> msg (cols 0..127) ----
    {
        bf16x8 Bf[2][4];
        #pragma unroll
        for (int t2 = 0; t2 < 2; ++t2)
            #pragma unroll
            for (int kk = 0; kk < 4; ++kk)
                Bf[t2][kk] = *(const bf16x8*)&We2F[(((2*w + t2)*4 + kk)*64 + l)*8];
        float b0[2];
        #pragma unroll
        for (int t2 = 0; t2 < 2; ++t2) b0[t2] = be2[(2*w + t2)*16 + m];
        #pragma unroll
        for (int mt = 0; mt < 4; ++mt) {
            bf16x8 a[4];
            #pragma unroll
            for (int kk = 0; kk < 4; ++kk)
                a[kk] = *(const bf16x8*)&A[mt*16 + m][128 + kk*32 + q*8];
            #pragma unroll
            for (int t2 = 0; t2 < 2; ++t2) {
                f32x4 c = { b0[t2], b0[t2], b0[t2], b0[t2] };
                #pragma unroll
                for (int kk = 0; kk < 4; ++kk)
                    c = __builtin_amdgcn_mfma_f32_16x16x32_bf16(a[kk], Bf[t2][kk], c, 0, 0, 0);
                int n = (2*w + t2)*16 + m;
                int rb = mt*16 + q*4;
                unsigned p0 = pk2bf(silu_f(c[0]), silu_f(c[1]));
                unsigned p1 = pk2bf(silu_f(c[2]), silu_f(c[3]));
                A[rb + 0][n] = (u16)p0;
                A[rb + 1][n] = (u16)(p0 >> 16);
                A[rb + 2][n] = (u16)p1;
                A[rb + 3][n] = (u16)(p1 >> 16);
            }
        }
    }
    __syncthreads();

    // ---- coord layer 1: t2 = silu(msg @ Wc1 + bc1); msg (cols 0..127) -> T (cols 128+) ----
    {
        bf16x8 Bf[2][4];
        #pragma unroll
        for (int t2 = 0; t2 < 2; ++t2)
            #pragma unroll
            for (int kk = 0; kk < 4; ++kk)
                Bf[t2][kk] = *(const bf16x8*)&Wc1F[(((2*w + t2)*4 + kk)*64 + l)*8];
        float b0[2];
        #pragma unroll
        for (int t2 = 0; t2 < 2; ++t2) b0[t2] = bc1[(2*w + t2)*16 + m];
        #pragma unroll
        for (int mt = 0; mt < 4; ++mt) {
            bf16x8 a[4];
            #pragma unroll
            for (int kk = 0; kk < 4; ++kk)
                a[kk] = *(const bf16x8*)&A[mt*16 + m][kk*32 + q*8];
            #pragma unroll
            for (int t2 = 0; t2 < 2; ++t2) {
                f32x4 c = { b0[t2], b0[t2], b0[t2], b0[t2] };
                #pragma unroll
                for (int kk = 0; kk < 4; ++kk)
                    c = __builtin_amdgcn_mfma_f32_16x16x32_bf16(a[kk], Bf[t2][kk], c, 0, 0, 0);
                int n = 128 + (2*w + t2)*16 + m;
                int rb = mt*16 + q*4;
                unsigned p0 = pk2bf(silu_f(c[0]), silu_f(c[1]));
                unsigned p1 = pk2bf(silu_f(c[2]), silu_f(c[3]));
                A[rb + 0][n] = (u16)p0;
                A[rb + 1][n] = (u16)(p0 >> 16);
                A[rb + 2][n] = (u16)p1;
                A[rb + 3][n] = (u16)(p1 >> 16);
            }
        }
    }
    __syncthreads();

    // ---- coord layer 2: w_e = clip(t2 . Wc2, -1, 1); pos scatter ----
    {
        int e = tid >> 2;
        int l4 = tid & 3;
        float p = 0.f;
        #pragma unroll
        for (int i = 0; i < 8; ++i) {
            int k = l4 * 32 + i * 4;
            u16x4 tv = *(const u16x4*)&A[e][128 + k];
            float4 wv = *(const float4*)&Wc2[k];
            p += bf2f(tv.x)*wv.x + bf2f(tv.y)*wv.y + bf2f(tv.z)*wv.z + bf2f(tv.w)*wv.w;
        }
        p += __shfl_xor(p, 1);
        p += __shfl_xor(p, 2);
        if (l4 == 0 && (e0 + e) < E) {
            float cw = fminf(1.0f, fmaxf(-1.0f, p));
            float s = cw / edist[e];
            int r = erow[e];
            atomicAdd(&pos_out[r*3+0], ediff[e][0] * s);
            atomicAdd(&pos_out[r*3+1], ediff[e][1] * s);
            atomicAdd(&pos_out[r*3+2], ediff[e][2] * s);
        }
    }

    // ---- tail: agg scatter from LDS msg — issued last, drains at retire ----
    if (BA) {
        #pragma unroll
        for (int e2 = 0; e2 < 16; ++e2) {
            int e = w * 16 + e2;
            if ((e0 + e) < E) {
                int r = erow[e];
                unsigned pk = *(const unsigned*)&A[e][l * 2];
                pk_agg_add(&aggb[(size_t)r * D + l * 2], pk);
            }
        }
    } else {
        #pragma unroll
        for (int e2 = 0; e2 < 16; ++e2) {
            int e = w * 16 + e2;
            if ((e0 + e) < E) {
                int r = erow[e];
                atomicAdd(&aggf[(size_t)r * D + l],      bf2f(A[e][l]));
                atomicAdd(&aggf[(size_t)r * D + l + 64], bf2f(A[e][l + 64]));
            }
        }
    }
}

// ---------------- node kernel: h_out = h + MLP([h|agg]) ----------------
template<int BA>
__global__ __launch_bounds__(256, 4) void egnn_node_mfma(
    const float* __restrict__ h,
    const u16* __restrict__ aggb, const float* __restrict__ aggf,
    const u16* __restrict__ Wn1F, const float* __restrict__ bn1,
    const u16* __restrict__ Wn2F, const float* __restrict__ bn2,
    float* __restrict__ out, int N)
{
    __shared__ u16 A[64][264];

    const int tid = threadIdx.x;
    const int w = tid >> 6, l = tid & 63;
    const int q = l >> 4, m = l & 15;
    const int n0 = blockIdx.x * 64;

    bf16x8 B1[2][8];
    #pragma unroll
    for (int t2 = 0; t2 < 2; ++t2)
        #pragma unroll
        for (int kk = 0; kk < 8; ++kk)
            B1[t2][kk] = *(const bf16x8*)&Wn1F[(((2*w + t2)*8 + kk)*64 + l)*8];

    // gather [h | agg] -> bf16 LDS
    #pragma unroll
    for (int p = 0; p < 16; ++p) {
        int nl = p * 4 + w;
        int node = n0 + nl; if (node >= N) node = N - 1;
        int f0 = (l & 31) * 4;
        if (l < 32) {
            float4 v = *(const float4*)(h + (size_t)node * D + f0);
            uint2 pk; pk.x = pk2bf(v.x, v.y); pk.y = pk2bf(v.z, v.w);
            *(uint2*)&A[nl][f0] = pk;
        } else if (BA) {
            u16x4 v = *(const u16x4*)&aggb[(size_t)node * D + f0];
            *(u16x4*)&A[nl][128 + f0] = v;
        } else {
            float4 v = *(const float4*)(aggf + (size_t)node * D + f0);
            uint2 pk; pk.x = pk2bf(v.x, v.y); pk.y = pk2bf(v.z, v.w);
            *(uint2*)&A[nl][128 + f0] = pk;
        }
    }
    __syncthreads();

    // ---- node layer 1: hold in regs, then overlay T onto agg half ----
    unsigned hold[4][2][2];
    {
        float b0[2];
        #pragma unroll
        for (int t2 = 0; t2 < 2; ++t2) b0[t2] = bn1[(2*w + t2)*16 + m];
        #pragma unroll
        for (int mt = 0; mt < 4; ++mt) {
            bf16x8 a[8];
            #pragma unroll
            for (int kk = 0; kk < 8; ++kk)
                a[kk] = *(const bf16x8*)&A[mt*16 + m][kk*32 + q*8];
            #pragma unroll
            for (int t2 = 0; t2 < 2; ++t2) {
                f32x4 c = { b0[t2], b0[t2], b0[t2], b0[t2] };
                #pragma unroll
                for (int kk = 0; kk < 8; ++kk)
                    c = __builtin_amdgcn_mfma_f32_16x16x32_bf16(a[kk], B1[t2][kk], c, 0, 0, 0);
                hold[mt][t2][0] = pk2bf(silu_f(c[0]), silu_f(c[1]));
                hold[mt][t2][1] = pk2bf(silu_f(c[2]), silu_f(c[3]));
            }
        }
    }
    __syncthreads();

    #pragma unroll
    for (int mt = 0; mt < 4; ++mt)
        #pragma unroll
        for (int t2 = 0; t2 < 2; ++t2) {
            int n = 128 + (2*w + t2)*16 + m;
            int rb = mt*16 + q*4;
            unsigned h0 = hold[mt][t2][0], h1 = hold[mt][t2][1];
            A[rb + 0][n] = (u16)h0;
            A[rb + 1][n] = (u16)(h0 >> 16);
            A[rb + 2][n] = (u16)h1;
            A[rb + 3][n] = (u16)(h1 >> 16);
        }
    __syncthreads();

    // ---- node layer 2 + residual: out = h + t1 @ Wn2 + bn2 (h from LDS bf16) ----
    {
        bf16x8 Bf[2][4];
        #pragma unroll
        for (int t2 = 0; t2 < 2; ++t2)
            #pragma unroll
            for (int kk = 0; kk < 4; ++kk)
                Bf[t2][kk] = *(const bf16x8*)&Wn2F[(((2*w + t2)*4 + kk)*64 + l)*8];
        float b0[2];
        #pragma unroll
        for (int t2 = 0; t2 < 2; ++t2) b0[t2] = bn2[(2*w + t2)*16 + m];
        #pragma unroll
        for (int mt = 0; mt < 4; ++mt) {
            bf16x8 a[4];
            #pragma unroll
            for (int kk = 0; kk < 4; ++kk)
                a[kk] = *(const bf16x8*)&A[mt*16 + m][128 + kk*32 + q*8];
            #pragma unroll
            for (int t2 = 0; t2 < 2; ++t2) {
                f32x4 c = { b0[t2], b0[t2], b0[t2], b0[t2] };
                #pragma unroll
                for (int kk = 0; kk < 4; ++kk)
                    c = __builtin_amdgcn_mfma_f32_16x16x32_bf16(a[kk], Bf[t2][kk], c, 0, 0, 0);
                int n = (2*w + t2)*16 + m;
                #pragma unroll
                for (int rg = 0; rg < 4; ++rg) {
                    int node = n0 + mt*16 + q*4 + rg;
                    if (node < N)
                        out[(size_t)node * D + n] =
                            bf2f(A[mt*16 + q*4 + rg][n]) + c[rg];
                }
            }
        }
    }
}

extern "C" void kernel_launch(void* const* d_in, const int* in_sizes, int n_in,
                              void* d_out, int out_size, void* d_ws, size_t ws_size,
                              hipStream_t stream)
{
    const float* h   = (const float*)d_in[0];
    const float* pos = (const float*)d_in[1];
    const int*   eidx= (const int*)d_in[2];
    const float* We1 = (const float*)d_in[3];
    const float* be1 = (const float*)d_in[4];
    const float* We2 = (const float*)d_in[5];
    const float* be2 = (const float*)d_in[6];
    const float* Wn1 = (const float*)d_in[7];
    const float* bn1 = (const float*)d_in[8];
    const float* Wn2 = (const float*)d_in[9];
    const float* bn2 = (const float*)d_in[10];
    const float* Wc1 = (const float*)d_in[11];
    const float* bc1 = (const float*)d_in[12];
    const float* Wc2 = (const float*)d_in[13];

    const int N = in_sizes[0] / D;
    const int E = in_sizes[2] / 2;

    float* out     = (float*)d_out;
    float* pos_out = out + (size_t)N * D;

    u16* ws = (u16*)d_ws;
    const u16* We1F = ws + FRAG_WE1;
    const u16* We2F = ws + FRAG_WE2;
    const u16* Wc1F = ws + FRAG_WC1;
    const u16* Wn1F = ws + FRAG_WN1;
    const u16* Wn2F = ws + FRAG_WN2;
    const float* We1r = (const float*)(ws + WE1R_OFF);

    u16*   aggb = ws + AGG_OFF;
    float* aggf = out;   // fallback: fp32 agg in out h-region

    const size_t need = ((size_t)AGG_OFF + (size_t)N * D) * 2;
    const bool ba = ws_size >= need;

    egnn_prep<<<128, 256, 0, stream>>>(We1, We2, Wc1, Wn1, Wn2, ws);
    if (ba) {
        egnn_init_ba<<<2048, 256, 0, stream>>>(pos, out, (uint4*)aggb, N);
        egnn_edge_mfma<1><<<(E + 63) / 64, 256, 0, stream>>>(
            h, pos, eidx, We1F, We1r, be1, We2F, be2, Wc1F, bc1, Wc2,
            aggb, aggf, pos_out, E);
        egnn_node_mfma<1><<<(N + 63) / 64, 256, 0, stream>>>(
            h, aggb, aggf, Wn1F, bn1, Wn2F, bn2, out, N);
    } else {
        egnn_init_f32<<<2048, 256, 0, stream>>>(pos, out, N);
        egnn_edge_mfma<0><<<(E + 63) / 64, 256, 0, stream>>>(
            h, pos, eidx, We1F, We1r, be1, We2F, be2, Wc1F, bc1, Wc2,
            aggb, aggf, pos_out, E);
        egnn_node_mfma<0><<<(N + 63) / 64, 256, 0, stream>>>(
            h, aggb, aggf, Wn1F, bn1, Wn2F, bn2, out, N);
    }
}